// Round 2
// baseline (1263.321 us; speedup 1.0000x reference)
//
#include <hip/hip_runtime.h>
#include <hip/hip_bf16.h>
#include <stdint.h>

#define NN 50000
#define NE 800000
#define EPS 1e-5f

typedef __attribute__((ext_vector_type(8))) short bf16x8;
typedef __attribute__((ext_vector_type(4))) float floatx4;

static __device__ __forceinline__ float bf2f(unsigned short u){
  union { unsigned int i; float f; } c; c.i = ((unsigned int)u) << 16; return c.f;
}
static __device__ __forceinline__ unsigned short f2bf(float f){
  union { float f; unsigned int i; } c; c.f = f;
  unsigned int x = c.i;
  return (unsigned short)((x + 0x7fffu + ((x >> 16) & 1u)) >> 16);
}

__global__ void k_zero(int* __restrict__ p, int n){
  int i = blockIdx.x * 256 + threadIdx.x;
  if(i < n) p[i] = 0;
}

// fused f32 -> bf16 converter for x + the 6 GEMM weight matrices (all bf16-valued, lossless)
#define CVT_X   3200000
#define CVT_W1  3212288
#define CVT_WL2 3228672
#define CVT_WR2 3245056
#define CVT_WL3 3261440
#define CVT_WR3 3277824
#define CVT_END 3290112
__global__ void k_cvt_all(const float* __restrict__ x,  const float* __restrict__ W1,
                          const float* __restrict__ Wl2, const float* __restrict__ Wr2,
                          const float* __restrict__ Wl3, const float* __restrict__ Wr3,
                          const float* __restrict__ W4,
                          unsigned short* __restrict__ xb,  unsigned short* __restrict__ W1b,
                          unsigned short* __restrict__ Wl2b, unsigned short* __restrict__ Wr2b,
                          unsigned short* __restrict__ Wl3b, unsigned short* __restrict__ Wr3b,
                          unsigned short* __restrict__ W4b){
  int i = blockIdx.x * 256 + threadIdx.x;
  if(i >= CVT_END) return;
  if(i < CVT_X)        xb[i] = f2bf(x[i]);
  else if(i < CVT_W1)  W1b[i - CVT_X]    = f2bf(W1[i - CVT_X]);
  else if(i < CVT_WL2) Wl2b[i - CVT_W1]  = f2bf(Wl2[i - CVT_W1]);
  else if(i < CVT_WR2) Wr2b[i - CVT_WL2] = f2bf(Wr2[i - CVT_WL2]);
  else if(i < CVT_WL3) Wl3b[i - CVT_WR2] = f2bf(Wl3[i - CVT_WR2]);
  else if(i < CVT_WR3) Wr3b[i - CVT_WL3] = f2bf(Wr3[i - CVT_WL3]);
  else                 W4b[i - CVT_WR3]  = f2bf(W4[i - CVT_WR3]);
}

__global__ void k_count(const int* __restrict__ ei, int* __restrict__ cnt){
  int e = blockIdx.x * 256 + threadIdx.x;
  if(e < NE) atomicAdd(&cnt[ei[NE + e]], 1);
}

// single-block exclusive scan of cnt[0..NN) -> rowptr, cursor; rowptr[NN]=NE
__global__ void k_scan(const int* __restrict__ cnt, int* __restrict__ rowptr, int* __restrict__ cursor){
  __shared__ int part[1024];
  int t = threadIdx.x;
  const int CH = (NN + 1023) / 1024;  // 49
  int lo = t * CH; if(lo > NN) lo = NN;
  int hi = lo + CH; if(hi > NN) hi = NN;
  int s = 0;
  for(int i = lo; i < hi; i++) s += cnt[i];
  part[t] = s;
  __syncthreads();
  for(int d = 1; d < 1024; d <<= 1){
    int v = (t >= d) ? part[t - d] : 0;
    __syncthreads();
    part[t] += v;
    __syncthreads();
  }
  int off = part[t] - s;  // exclusive prefix of this thread's chunk
  for(int i = lo; i < hi; i++){ rowptr[i] = off; cursor[i] = off; off += cnt[i]; }
  if(t == 1023) rowptr[NN] = part[1023];
}

__global__ void k_fill(const int* __restrict__ ei, int* __restrict__ cursor,
                       int* __restrict__ adj_src, int* __restrict__ adj_eid){
  int e = blockIdx.x * 256 + threadIdx.x;
  if(e >= NE) return;
  int src = ei[e];
  int dst = ei[NE + e];
  int p = atomicAdd(&cursor[dst], 1);
  adj_src[p] = src;
  if(adj_eid) adj_eid[p] = e;
}

// conv1 aggregation: mean over incoming edges of [x[src](64) | edge_attr[e](32)] -> agg bf16 [NN,96]
// f32 sources; one wave per node; lane l < 32 owns x dims 2l,2l+1; lanes 32..47 own ea dims
__global__ void k_agg1(const int* __restrict__ rowptr, const int* __restrict__ adj_src,
                       const int* __restrict__ adj_eid,
                       const float* __restrict__ x, const float* __restrict__ ea,
                       unsigned short* __restrict__ agg){
  int w = (blockIdx.x * blockDim.x + threadIdx.x) >> 6;
  int lane = threadIdx.x & 63;
  if(w >= NN) return;
  int r0 = rowptr[w], r1 = rowptr[w + 1];
  float ax = 0.f, ay = 0.f;
  if(lane < 32){
    int c = 2 * lane;
    for(int k = r0; k < r1; k++){
      int s = adj_src[k];
      float2 v = *(const float2*)(x + s * 64 + c);
      ax += v.x; ay += v.y;
    }
  } else if(lane < 48){
    int c = 2 * (lane - 32);
    for(int k = r0; k < r1; k++){
      int e = adj_eid[k];
      float2 v = *(const float2*)(ea + e * 32 + c);
      ax += v.x; ay += v.y;
    }
  }
  if(lane < 48){
    int deg = r1 - r0;
    float inv = 1.0f / (float)(deg > 0 ? deg : 1);
    int col = (lane < 32) ? 2 * lane : 64 + 2 * (lane - 32);
    unsigned int packed = (unsigned int)f2bf(ax * inv) | ((unsigned int)f2bf(ay * inv) << 16);
    *(unsigned int*)(agg + w * 96 + col) = packed;
  }
}

// mean-aggregate 128-dim bf16 node features via CSR; one wave per node, lane l owns dims 2l,2l+1
__global__ void k_aggH(const int* __restrict__ rowptr, const int* __restrict__ adj_src,
                       const unsigned short* __restrict__ h, unsigned short* __restrict__ agg){
  int w = (blockIdx.x * blockDim.x + threadIdx.x) >> 6;
  int lane = threadIdx.x & 63;
  if(w >= NN) return;
  int r0 = rowptr[w], r1 = rowptr[w + 1];
  float ax = 0.f, ay = 0.f;
  int c = 2 * lane;
  int k = r0;
  int s_next = (k < r1) ? adj_src[k] : 0;
  while(k < r1){
    int s = s_next;
    k++;
    s_next = (k < r1) ? adj_src[k] : 0;  // prefetch next index while gather is in flight
    unsigned int v = *(const unsigned int*)(h + s * 128 + c);
    ax += bf2f((unsigned short)(v & 0xffffu));
    ay += bf2f((unsigned short)(v >> 16));
  }
  int deg = r1 - r0;
  float inv = 1.0f / (float)(deg > 0 ? deg : 1);
  unsigned int packed = (unsigned int)f2bf(ax * inv) | ((unsigned int)f2bf(ay * inv) << 16);
  *(unsigned int*)(agg + w * 128 + c) = packed;
}

// conv1 dense part: h1 = relu(bn(relu(mask_deg(agg @ W1^T + b1))))
// one wave = 16 nodes x 16 outs tile; M-tiles 3125 x N-tiles 8
__global__ void k_lin1(const unsigned short* __restrict__ agg, const unsigned short* __restrict__ W1,
                       const float* __restrict__ b1,
                       const float* __restrict__ g1, const float* __restrict__ be1,
                       const float* __restrict__ m1, const float* __restrict__ v1,
                       const int* __restrict__ rowptr, unsigned short* __restrict__ h1){
  int wave = (blockIdx.x * blockDim.x + threadIdx.x) >> 6;
  int lane = threadIdx.x & 63;
  int mt = wave >> 3, nt = wave & 7;
  if(mt >= 3125) return;
  int node0 = mt * 16;
  int col = lane & 15, quad = lane >> 4;
  int o = nt * 16 + col;
  int arow = node0 + col;
  floatx4 acc = {0.f, 0.f, 0.f, 0.f};
  #pragma unroll
  for(int kc = 0; kc < 3; kc++){
    bf16x8 a = *(const bf16x8*)(agg + arow * 96 + kc * 32 + quad * 8);
    bf16x8 b = *(const bf16x8*)(W1 + o * 96 + kc * 32 + quad * 8);
    acc = __builtin_amdgcn_mfma_f32_16x16x32_bf16(a, b, acc, 0, 0, 0);
  }
  float bb = b1[o];
  float sc = g1[o] * rsqrtf(v1[o] + EPS);
  float mv = m1[o], bev = be1[o];
  #pragma unroll
  for(int r = 0; r < 4; r++){
    int node = node0 + quad * 4 + r;
    int deg = rowptr[node + 1] - rowptr[node];
    float pre = (deg > 0) ? (acc[r] + bb) : 0.0f;   // ref: empty segment -> mean 0, bias never added
    float t = fmaxf(pre, 0.f);
    float bn = sc * (t - mv) + bev;
    h1[node * 128 + o] = f2bf(fmaxf(bn, 0.f));
  }
}

// SAGE: hout = relu(bn(agg @ Wl^T + bl + hin @ Wr^T))
__global__ void k_sage(const unsigned short* __restrict__ agg, const unsigned short* __restrict__ hin,
                       const unsigned short* __restrict__ Wl, const float* __restrict__ bl,
                       const unsigned short* __restrict__ Wr,
                       const float* __restrict__ g, const float* __restrict__ be,
                       const float* __restrict__ m, const float* __restrict__ v,
                       unsigned short* __restrict__ hout){
  int wave = (blockIdx.x * blockDim.x + threadIdx.x) >> 6;
  int lane = threadIdx.x & 63;
  int mt = wave >> 3, nt = wave & 7;
  if(mt >= 3125) return;
  int node0 = mt * 16;
  int col = lane & 15, quad = lane >> 4;
  int o = nt * 16 + col;
  int arow = node0 + col;
  floatx4 acc = {0.f, 0.f, 0.f, 0.f};
  #pragma unroll
  for(int kc = 0; kc < 4; kc++){
    bf16x8 a = *(const bf16x8*)(agg + arow * 128 + kc * 32 + quad * 8);
    bf16x8 b = *(const bf16x8*)(Wl + o * 128 + kc * 32 + quad * 8);
    acc = __builtin_amdgcn_mfma_f32_16x16x32_bf16(a, b, acc, 0, 0, 0);
  }
  #pragma unroll
  for(int kc = 0; kc < 4; kc++){
    bf16x8 a = *(const bf16x8*)(hin + arow * 128 + kc * 32 + quad * 8);
    bf16x8 b = *(const bf16x8*)(Wr + o * 128 + kc * 32 + quad * 8);
    acc = __builtin_amdgcn_mfma_f32_16x16x32_bf16(a, b, acc, 0, 0, 0);
  }
  float blv = bl[o];
  float sc = g[o] * rsqrtf(v[o] + EPS);
  float mv = m[o], bev = be[o];
  #pragma unroll
  for(int r = 0; r < 4; r++){
    int node = node0 + quad * 4 + r;
    float pre = acc[r] + blv;
    float bn = sc * (pre - mv) + bev;
    hout[node * 128 + o] = f2bf(fmaxf(bn, 0.f));
  }
}

// readout: z = relu([h3 | x] @ W4^T + b4) (64), out = z @ W5^T + b5  (f32 out)
__global__ void k_readout(const unsigned short* __restrict__ h3, const unsigned short* __restrict__ xb,
                          const unsigned short* __restrict__ W4, const float* __restrict__ b4,
                          const float* __restrict__ W5, const float* __restrict__ b5,
                          float* __restrict__ out){
  int wave = (blockIdx.x * blockDim.x + threadIdx.x) >> 6;
  int lane = threadIdx.x & 63;
  if(wave >= 3125) return;
  int node0 = wave * 16;
  int col = lane & 15, quad = lane >> 4;
  int arow = node0 + col;
  float partial[4] = {0.f, 0.f, 0.f, 0.f};
  #pragma unroll
  for(int nt = 0; nt < 4; nt++){
    int o = nt * 16 + col;
    floatx4 acc = {0.f, 0.f, 0.f, 0.f};
    #pragma unroll
    for(int kc = 0; kc < 4; kc++){   // h3 part, K=128
      bf16x8 a = *(const bf16x8*)(h3 + arow * 128 + kc * 32 + quad * 8);
      bf16x8 b = *(const bf16x8*)(W4 + o * 192 + kc * 32 + quad * 8);
      acc = __builtin_amdgcn_mfma_f32_16x16x32_bf16(a, b, acc, 0, 0, 0);
    }
    #pragma unroll
    for(int kc = 0; kc < 2; kc++){   // x part, K=64, W4 cols 128..191
      bf16x8 a = *(const bf16x8*)(xb + arow * 64 + kc * 32 + quad * 8);
      bf16x8 b = *(const bf16x8*)(W4 + o * 192 + 128 + kc * 32 + quad * 8);
      acc = __builtin_amdgcn_mfma_f32_16x16x32_bf16(a, b, acc, 0, 0, 0);
    }
    float bb = b4[o];
    float w5 = W5[o];
    #pragma unroll
    for(int r = 0; r < 4; r++)
      partial[r] += fmaxf(acc[r] + bb, 0.f) * w5;
  }
  // sum over the 16 cols within each quad (rows identical across those lanes)
  #pragma unroll
  for(int d = 1; d < 16; d <<= 1){
    #pragma unroll
    for(int r = 0; r < 4; r++)
      partial[r] += __shfl_xor(partial[r], d, 64);
  }
  if(col == 0){
    float b5f = b5[0];
    #pragma unroll
    for(int r = 0; r < 4; r++)
      out[node0 + quad * 4 + r] = partial[r] + b5f;
  }
}

extern "C" void kernel_launch(void* const* d_in, const int* in_sizes, int n_in,
                              void* d_out, int out_size, void* d_ws, size_t ws_size,
                              hipStream_t stream) {
  const float* x   = (const float*)d_in[0];
  const int* ei0   = (const int*)d_in[1];
  const int* ei1   = (const int*)d_in[2];
  const int* ei2   = (const int*)d_in[3];
  const float* ea  = (const float*)d_in[4];
  const float* W1  = (const float*)d_in[5];
  const float* b1  = (const float*)d_in[6];
  const float* g1  = (const float*)d_in[7];
  const float* be1 = (const float*)d_in[8];
  const float* m1  = (const float*)d_in[9];
  const float* v1  = (const float*)d_in[10];
  const float* Wl2 = (const float*)d_in[11];
  const float* bl2 = (const float*)d_in[12];
  const float* Wr2 = (const float*)d_in[13];
  const float* g2  = (const float*)d_in[14];
  const float* be2 = (const float*)d_in[15];
  const float* m2  = (const float*)d_in[16];
  const float* v2  = (const float*)d_in[17];
  const float* Wl3 = (const float*)d_in[18];
  const float* bl3 = (const float*)d_in[19];
  const float* Wr3 = (const float*)d_in[20];
  const float* g3  = (const float*)d_in[21];
  const float* be3 = (const float*)d_in[22];
  const float* m3  = (const float*)d_in[23];
  const float* v3  = (const float*)d_in[24];
  const float* W4  = (const float*)d_in[25];
  const float* b4  = (const float*)d_in[26];
  const float* W5  = (const float*)d_in[27];
  const float* b5  = (const float*)d_in[28];

  char* ws = (char*)d_ws;
  size_t off = 0;
  auto alloc = [&](size_t bytes) -> void* {
    void* p = (void*)(ws + off);
    off += (bytes + 255) & ~(size_t)255;
    return p;
  };
  int* rowptr  = (int*)alloc((NN + 1) * sizeof(int));
  int* cnt     = (int*)alloc(NN * sizeof(int));
  int* cursor  = (int*)alloc(NN * sizeof(int));
  int* adj_src = (int*)alloc(NE * sizeof(int));
  int* adj_eid = (int*)alloc(NE * sizeof(int));
  unsigned short* agg1 = (unsigned short*)alloc((size_t)NN * 96 * 2);
  unsigned short* aggH = (unsigned short*)alloc((size_t)NN * 128 * 2);
  unsigned short* h1   = (unsigned short*)alloc((size_t)NN * 128 * 2);
  unsigned short* h2   = (unsigned short*)alloc((size_t)NN * 128 * 2);
  unsigned short* h3   = (unsigned short*)alloc((size_t)NN * 128 * 2);
  unsigned short* xb   = (unsigned short*)alloc((size_t)NN * 64 * 2);
  unsigned short* W1b  = (unsigned short*)alloc(12288 * 2);
  unsigned short* Wl2b = (unsigned short*)alloc(16384 * 2);
  unsigned short* Wr2b = (unsigned short*)alloc(16384 * 2);
  unsigned short* Wl3b = (unsigned short*)alloc(16384 * 2);
  unsigned short* Wr3b = (unsigned short*)alloc(16384 * 2);
  unsigned short* W4b  = (unsigned short*)alloc(12288 * 2);

  const int gE    = (NE + 255) / 256;          // 3125
  const int gN    = (NN + 255) / 256;          // 196
  const int gAgg  = (NN * 64) / 256;           // 12500
  const int gTile = (3125 * 8 * 64) / 256;     // 6250
  const int gRead = (3125 * 64 + 255) / 256;   // 782
  const int gCvt  = (CVT_END + 255) / 256;

  k_cvt_all<<<gCvt, 256, 0, stream>>>(x, W1, Wl2, Wr2, Wl3, Wr3, W4,
                                      xb, W1b, Wl2b, Wr2b, Wl3b, Wr3b, W4b);

  // ---- layer 1 (conv1) ----
  k_zero<<<gN, 256, 0, stream>>>(cnt, NN);
  k_count<<<gE, 256, 0, stream>>>(ei0, cnt);
  k_scan<<<1, 1024, 0, stream>>>(cnt, rowptr, cursor);
  k_fill<<<gE, 256, 0, stream>>>(ei0, cursor, adj_src, adj_eid);
  k_agg1<<<gAgg, 256, 0, stream>>>(rowptr, adj_src, adj_eid, x, ea, agg1);
  k_lin1<<<gTile, 256, 0, stream>>>(agg1, W1b, b1, g1, be1, m1, v1, rowptr, h1);

  // ---- layer 2 (SAGE) ----
  k_zero<<<gN, 256, 0, stream>>>(cnt, NN);
  k_count<<<gE, 256, 0, stream>>>(ei1, cnt);
  k_scan<<<1, 1024, 0, stream>>>(cnt, rowptr, cursor);
  k_fill<<<gE, 256, 0, stream>>>(ei1, cursor, adj_src, (int*)nullptr);
  k_aggH<<<gAgg, 256, 0, stream>>>(rowptr, adj_src, h1, aggH);
  k_sage<<<gTile, 256, 0, stream>>>(aggH, h1, Wl2b, bl2, Wr2b, g2, be2, m2, v2, h2);

  // ---- layer 3 (SAGE) ----
  k_zero<<<gN, 256, 0, stream>>>(cnt, NN);
  k_count<<<gE, 256, 0, stream>>>(ei2, cnt);
  k_scan<<<1, 1024, 0, stream>>>(cnt, rowptr, cursor);
  k_fill<<<gE, 256, 0, stream>>>(ei2, cursor, adj_src, (int*)nullptr);
  k_aggH<<<gAgg, 256, 0, stream>>>(rowptr, adj_src, h2, aggH);
  k_sage<<<gTile, 256, 0, stream>>>(aggH, h2, Wl3b, bl3, Wr3b, g3, be3, m3, v3, h3);

  // ---- readout ----
  k_readout<<<gRead, 256, 0, stream>>>(h3, xb, W4b, b4, W5, b5, (float*)d_out);

  (void)in_sizes; (void)n_in; (void)out_size; (void)ws_size;
}

// Round 3
// 837.473 us; speedup vs baseline: 1.5085x; 1.5085x over previous
//
#include <hip/hip_runtime.h>
#include <hip/hip_bf16.h>
#include <stdint.h>

#define NN 50000
#define NE 800000
#define EPS 1e-5f

typedef __attribute__((ext_vector_type(8))) short bf16x8;
typedef __attribute__((ext_vector_type(4))) float floatx4;

static __device__ __forceinline__ float bf2f(unsigned short u){
  union { unsigned int i; float f; } c; c.i = ((unsigned int)u) << 16; return c.f;
}
static __device__ __forceinline__ unsigned short f2bf(float f){
  union { float f; unsigned int i; } c; c.f = f;
  unsigned int x = c.i;
  return (unsigned short)((x + 0x7fffu + ((x >> 16) & 1u)) >> 16);
}

__global__ void k_zero(int* __restrict__ p, int n){
  int i = blockIdx.x * 256 + threadIdx.x;
  if(i < n) p[i] = 0;
}

// fused f32 -> bf16 converter for x + the 6 GEMM weight matrices (all bf16-valued, lossless)
#define CVT_X   3200000
#define CVT_W1  3212288
#define CVT_WL2 3228672
#define CVT_WR2 3245056
#define CVT_WL3 3261440
#define CVT_WR3 3277824
#define CVT_END 3290112
__global__ void k_cvt_all(const float* __restrict__ x,  const float* __restrict__ W1,
                          const float* __restrict__ Wl2, const float* __restrict__ Wr2,
                          const float* __restrict__ Wl3, const float* __restrict__ Wr3,
                          const float* __restrict__ W4,
                          unsigned short* __restrict__ xb,  unsigned short* __restrict__ W1b,
                          unsigned short* __restrict__ Wl2b, unsigned short* __restrict__ Wr2b,
                          unsigned short* __restrict__ Wl3b, unsigned short* __restrict__ Wr3b,
                          unsigned short* __restrict__ W4b){
  int i = blockIdx.x * 256 + threadIdx.x;
  if(i >= CVT_END) return;
  if(i < CVT_X)        xb[i] = f2bf(x[i]);
  else if(i < CVT_W1)  W1b[i - CVT_X]    = f2bf(W1[i - CVT_X]);
  else if(i < CVT_WL2) Wl2b[i - CVT_W1]  = f2bf(Wl2[i - CVT_W1]);
  else if(i < CVT_WR2) Wr2b[i - CVT_WL2] = f2bf(Wr2[i - CVT_WL2]);
  else if(i < CVT_WL3) Wl3b[i - CVT_WR2] = f2bf(Wl3[i - CVT_WR2]);
  else if(i < CVT_WR3) Wr3b[i - CVT_WL3] = f2bf(Wr3[i - CVT_WL3]);
  else                 W4b[i - CVT_WR3]  = f2bf(W4[i - CVT_WR3]);
}

// fused per-layer degree count: grid.y = layer
__global__ void k_count3(const int* __restrict__ ei0, const int* __restrict__ ei1,
                         const int* __restrict__ ei2, int* __restrict__ cnt3){
  int e = blockIdx.x * 256 + threadIdx.x;
  if(e >= NE) return;
  int L = blockIdx.y;
  const int* ei = (L == 0) ? ei0 : (L == 1) ? ei1 : ei2;
  atomicAdd(&cnt3[L * NN + ei[NE + e]], 1);
}

// 3 blocks, one per layer: exclusive scan of cnt -> rowptr, cursor; rowptr[NN]=NE
__global__ void k_scan3(const int* __restrict__ cnt3, int* __restrict__ rowptr3, int* __restrict__ cursor3){
  __shared__ int part[1024];
  int L = blockIdx.x;
  const int* cnt = cnt3 + L * NN;
  int* rowptr = rowptr3 + L * (NN + 1);
  int* cursor = cursor3 + L * NN;
  int t = threadIdx.x;
  const int CH = (NN + 1023) / 1024;  // 49
  int lo = t * CH; if(lo > NN) lo = NN;
  int hi = lo + CH; if(hi > NN) hi = NN;
  int s = 0;
  for(int i = lo; i < hi; i++) s += cnt[i];
  part[t] = s;
  __syncthreads();
  for(int d = 1; d < 1024; d <<= 1){
    int v = (t >= d) ? part[t - d] : 0;
    __syncthreads();
    part[t] += v;
    __syncthreads();
  }
  int off = part[t] - s;  // exclusive prefix of this thread's chunk
  for(int i = lo; i < hi; i++){ rowptr[i] = off; cursor[i] = off; off += cnt[i]; }
  if(t == 1023) rowptr[NN] = part[1023];
}

__global__ void k_fill3(const int* __restrict__ ei0, const int* __restrict__ ei1,
                        const int* __restrict__ ei2, int* __restrict__ cursor3,
                        int* __restrict__ a0, int* __restrict__ a1, int* __restrict__ a2,
                        int* __restrict__ adj_eid){
  int e = blockIdx.x * 256 + threadIdx.x;
  if(e >= NE) return;
  int L = blockIdx.y;
  const int* ei = (L == 0) ? ei0 : (L == 1) ? ei1 : ei2;
  int* adj = (L == 0) ? a0 : (L == 1) ? a1 : a2;
  int src = ei[e];
  int dst = ei[NE + e];
  int p = atomicAdd(&cursor3[L * NN + dst], 1);
  adj[p] = src;
  if(L == 0) adj_eid[p] = e;
}

// conv1 aggregation: mean over incoming edges of [x[src](64, bf16) | edge_attr[e](32, f32)]
// -> agg bf16 [NN,96]. One wave per node; lanes 0-31 own x dims 2l,2l+1; lanes 32-47 ea dims.
// 8-way MLP unroll: batch index loads, then 8 gathers in flight.
__global__ void k_agg1(const int* __restrict__ rowptr, const int* __restrict__ adj_src,
                       const int* __restrict__ adj_eid,
                       const unsigned short* __restrict__ xb, const float* __restrict__ ea,
                       unsigned short* __restrict__ agg){
  int w = (blockIdx.x * blockDim.x + threadIdx.x) >> 6;
  int lane = threadIdx.x & 63;
  if(w >= NN) return;
  int r0 = rowptr[w], r1 = rowptr[w + 1];
  float ax = 0.f, ay = 0.f;
  if(lane < 32){
    int c = 2 * lane;
    int k = r0;
    for(; k + 8 <= r1; k += 8){
      int s[8]; unsigned int v[8];
      #pragma unroll
      for(int j = 0; j < 8; j++) s[j] = adj_src[k + j];
      #pragma unroll
      for(int j = 0; j < 8; j++) v[j] = *(const unsigned int*)(xb + s[j] * 64 + c);
      #pragma unroll
      for(int j = 0; j < 8; j++){ ax += bf2f((unsigned short)(v[j] & 0xffffu)); ay += bf2f((unsigned short)(v[j] >> 16)); }
    }
    if(k + 4 <= r1){
      int s[4]; unsigned int v[4];
      #pragma unroll
      for(int j = 0; j < 4; j++) s[j] = adj_src[k + j];
      #pragma unroll
      for(int j = 0; j < 4; j++) v[j] = *(const unsigned int*)(xb + s[j] * 64 + c);
      #pragma unroll
      for(int j = 0; j < 4; j++){ ax += bf2f((unsigned short)(v[j] & 0xffffu)); ay += bf2f((unsigned short)(v[j] >> 16)); }
      k += 4;
    }
    for(; k < r1; k++){
      unsigned int v = *(const unsigned int*)(xb + adj_src[k] * 64 + c);
      ax += bf2f((unsigned short)(v & 0xffffu)); ay += bf2f((unsigned short)(v >> 16));
    }
  } else if(lane < 48){
    int c = 2 * (lane - 32);
    int k = r0;
    for(; k + 8 <= r1; k += 8){
      int e[8]; float2 v[8];
      #pragma unroll
      for(int j = 0; j < 8; j++) e[j] = adj_eid[k + j];
      #pragma unroll
      for(int j = 0; j < 8; j++) v[j] = *(const float2*)(ea + e[j] * 32 + c);
      #pragma unroll
      for(int j = 0; j < 8; j++){ ax += v[j].x; ay += v[j].y; }
    }
    if(k + 4 <= r1){
      int e[4]; float2 v[4];
      #pragma unroll
      for(int j = 0; j < 4; j++) e[j] = adj_eid[k + j];
      #pragma unroll
      for(int j = 0; j < 4; j++) v[j] = *(const float2*)(ea + e[j] * 32 + c);
      #pragma unroll
      for(int j = 0; j < 4; j++){ ax += v[j].x; ay += v[j].y; }
      k += 4;
    }
    for(; k < r1; k++){
      float2 v = *(const float2*)(ea + adj_eid[k] * 32 + c);
      ax += v.x; ay += v.y;
    }
  }
  if(lane < 48){
    int deg = r1 - r0;
    float inv = 1.0f / (float)(deg > 0 ? deg : 1);
    int col = (lane < 32) ? 2 * lane : 64 + 2 * (lane - 32);
    unsigned int packed = (unsigned int)f2bf(ax * inv) | ((unsigned int)f2bf(ay * inv) << 16);
    *(unsigned int*)(agg + w * 96 + col) = packed;
  }
}

// mean-aggregate 128-dim bf16 node features via CSR; one wave per node, lane l owns dims 2l,2l+1
// 8-way MLP unroll
__global__ void k_aggH(const int* __restrict__ rowptr, const int* __restrict__ adj_src,
                       const unsigned short* __restrict__ h, unsigned short* __restrict__ agg){
  int w = (blockIdx.x * blockDim.x + threadIdx.x) >> 6;
  int lane = threadIdx.x & 63;
  if(w >= NN) return;
  int r0 = rowptr[w], r1 = rowptr[w + 1];
  float ax = 0.f, ay = 0.f;
  int c = 2 * lane;
  int k = r0;
  for(; k + 8 <= r1; k += 8){
    int s[8]; unsigned int v[8];
    #pragma unroll
    for(int j = 0; j < 8; j++) s[j] = adj_src[k + j];
    #pragma unroll
    for(int j = 0; j < 8; j++) v[j] = *(const unsigned int*)(h + s[j] * 128 + c);
    #pragma unroll
    for(int j = 0; j < 8; j++){ ax += bf2f((unsigned short)(v[j] & 0xffffu)); ay += bf2f((unsigned short)(v[j] >> 16)); }
  }
  if(k + 4 <= r1){
    int s[4]; unsigned int v[4];
    #pragma unroll
    for(int j = 0; j < 4; j++) s[j] = adj_src[k + j];
    #pragma unroll
    for(int j = 0; j < 4; j++) v[j] = *(const unsigned int*)(h + s[j] * 128 + c);
    #pragma unroll
    for(int j = 0; j < 4; j++){ ax += bf2f((unsigned short)(v[j] & 0xffffu)); ay += bf2f((unsigned short)(v[j] >> 16)); }
    k += 4;
  }
  for(; k < r1; k++){
    unsigned int v = *(const unsigned int*)(h + adj_src[k] * 128 + c);
    ax += bf2f((unsigned short)(v & 0xffffu)); ay += bf2f((unsigned short)(v >> 16));
  }
  int deg = r1 - r0;
  float inv = 1.0f / (float)(deg > 0 ? deg : 1);
  unsigned int packed = (unsigned int)f2bf(ax * inv) | ((unsigned int)f2bf(ay * inv) << 16);
  *(unsigned int*)(agg + w * 128 + c) = packed;
}

// conv1 dense part: h1 = relu(bn(relu(mask_deg(agg @ W1^T + b1))))
__global__ void k_lin1(const unsigned short* __restrict__ agg, const unsigned short* __restrict__ W1,
                       const float* __restrict__ b1,
                       const float* __restrict__ g1, const float* __restrict__ be1,
                       const float* __restrict__ m1, const float* __restrict__ v1,
                       const int* __restrict__ rowptr, unsigned short* __restrict__ h1){
  int wave = (blockIdx.x * blockDim.x + threadIdx.x) >> 6;
  int lane = threadIdx.x & 63;
  int mt = wave >> 3, nt = wave & 7;
  if(mt >= 3125) return;
  int node0 = mt * 16;
  int col = lane & 15, quad = lane >> 4;
  int o = nt * 16 + col;
  int arow = node0 + col;
  floatx4 acc = {0.f, 0.f, 0.f, 0.f};
  #pragma unroll
  for(int kc = 0; kc < 3; kc++){
    bf16x8 a = *(const bf16x8*)(agg + arow * 96 + kc * 32 + quad * 8);
    bf16x8 b = *(const bf16x8*)(W1 + o * 96 + kc * 32 + quad * 8);
    acc = __builtin_amdgcn_mfma_f32_16x16x32_bf16(a, b, acc, 0, 0, 0);
  }
  float bb = b1[o];
  float sc = g1[o] * rsqrtf(v1[o] + EPS);
  float mv = m1[o], bev = be1[o];
  #pragma unroll
  for(int r = 0; r < 4; r++){
    int node = node0 + quad * 4 + r;
    int deg = rowptr[node + 1] - rowptr[node];
    float pre = (deg > 0) ? (acc[r] + bb) : 0.0f;   // ref: empty segment -> mean 0, bias never added
    float t = fmaxf(pre, 0.f);
    float bn = sc * (t - mv) + bev;
    h1[node * 128 + o] = f2bf(fmaxf(bn, 0.f));
  }
}

// SAGE: hout = relu(bn(agg @ Wl^T + bl + hin @ Wr^T))
__global__ void k_sage(const unsigned short* __restrict__ agg, const unsigned short* __restrict__ hin,
                       const unsigned short* __restrict__ Wl, const float* __restrict__ bl,
                       const unsigned short* __restrict__ Wr,
                       const float* __restrict__ g, const float* __restrict__ be,
                       const float* __restrict__ m, const float* __restrict__ v,
                       unsigned short* __restrict__ hout){
  int wave = (blockIdx.x * blockDim.x + threadIdx.x) >> 6;
  int lane = threadIdx.x & 63;
  int mt = wave >> 3, nt = wave & 7;
  if(mt >= 3125) return;
  int node0 = mt * 16;
  int col = lane & 15, quad = lane >> 4;
  int o = nt * 16 + col;
  int arow = node0 + col;
  floatx4 acc = {0.f, 0.f, 0.f, 0.f};
  #pragma unroll
  for(int kc = 0; kc < 4; kc++){
    bf16x8 a = *(const bf16x8*)(agg + arow * 128 + kc * 32 + quad * 8);
    bf16x8 b = *(const bf16x8*)(Wl + o * 128 + kc * 32 + quad * 8);
    acc = __builtin_amdgcn_mfma_f32_16x16x32_bf16(a, b, acc, 0, 0, 0);
  }
  #pragma unroll
  for(int kc = 0; kc < 4; kc++){
    bf16x8 a = *(const bf16x8*)(hin + arow * 128 + kc * 32 + quad * 8);
    bf16x8 b = *(const bf16x8*)(Wr + o * 128 + kc * 32 + quad * 8);
    acc = __builtin_amdgcn_mfma_f32_16x16x32_bf16(a, b, acc, 0, 0, 0);
  }
  float blv = bl[o];
  float sc = g[o] * rsqrtf(v[o] + EPS);
  float mv = m[o], bev = be[o];
  #pragma unroll
  for(int r = 0; r < 4; r++){
    int node = node0 + quad * 4 + r;
    float pre = acc[r] + blv;
    float bn = sc * (pre - mv) + bev;
    hout[node * 128 + o] = f2bf(fmaxf(bn, 0.f));
  }
}

// readout: z = relu([h3 | x] @ W4^T + b4) (64), out = z @ W5^T + b5  (f32 out)
__global__ void k_readout(const unsigned short* __restrict__ h3, const unsigned short* __restrict__ xb,
                          const unsigned short* __restrict__ W4, const float* __restrict__ b4,
                          const float* __restrict__ W5, const float* __restrict__ b5,
                          float* __restrict__ out){
  int wave = (blockIdx.x * blockDim.x + threadIdx.x) >> 6;
  int lane = threadIdx.x & 63;
  if(wave >= 3125) return;
  int node0 = wave * 16;
  int col = lane & 15, quad = lane >> 4;
  int arow = node0 + col;
  float partial[4] = {0.f, 0.f, 0.f, 0.f};
  #pragma unroll
  for(int nt = 0; nt < 4; nt++){
    int o = nt * 16 + col;
    floatx4 acc = {0.f, 0.f, 0.f, 0.f};
    #pragma unroll
    for(int kc = 0; kc < 4; kc++){   // h3 part, K=128
      bf16x8 a = *(const bf16x8*)(h3 + arow * 128 + kc * 32 + quad * 8);
      bf16x8 b = *(const bf16x8*)(W4 + o * 192 + kc * 32 + quad * 8);
      acc = __builtin_amdgcn_mfma_f32_16x16x32_bf16(a, b, acc, 0, 0, 0);
    }
    #pragma unroll
    for(int kc = 0; kc < 2; kc++){   // x part, K=64, W4 cols 128..191
      bf16x8 a = *(const bf16x8*)(xb + arow * 64 + kc * 32 + quad * 8);
      bf16x8 b = *(const bf16x8*)(W4 + o * 192 + 128 + kc * 32 + quad * 8);
      acc = __builtin_amdgcn_mfma_f32_16x16x32_bf16(a, b, acc, 0, 0, 0);
    }
    float bb = b4[o];
    float w5 = W5[o];
    #pragma unroll
    for(int r = 0; r < 4; r++)
      partial[r] += fmaxf(acc[r] + bb, 0.f) * w5;
  }
  #pragma unroll
  for(int d = 1; d < 16; d <<= 1){
    #pragma unroll
    for(int r = 0; r < 4; r++)
      partial[r] += __shfl_xor(partial[r], d, 64);
  }
  if(col == 0){
    float b5f = b5[0];
    #pragma unroll
    for(int r = 0; r < 4; r++)
      out[node0 + quad * 4 + r] = partial[r] + b5f;
  }
}

extern "C" void kernel_launch(void* const* d_in, const int* in_sizes, int n_in,
                              void* d_out, int out_size, void* d_ws, size_t ws_size,
                              hipStream_t stream) {
  const float* x   = (const float*)d_in[0];
  const int* ei0   = (const int*)d_in[1];
  const int* ei1   = (const int*)d_in[2];
  const int* ei2   = (const int*)d_in[3];
  const float* ea  = (const float*)d_in[4];
  const float* W1  = (const float*)d_in[5];
  const float* b1  = (const float*)d_in[6];
  const float* g1  = (const float*)d_in[7];
  const float* be1 = (const float*)d_in[8];
  const float* m1  = (const float*)d_in[9];
  const float* v1  = (const float*)d_in[10];
  const float* Wl2 = (const float*)d_in[11];
  const float* bl2 = (const float*)d_in[12];
  const float* Wr2 = (const float*)d_in[13];
  const float* g2  = (const float*)d_in[14];
  const float* be2 = (const float*)d_in[15];
  const float* m2  = (const float*)d_in[16];
  const float* v2  = (const float*)d_in[17];
  const float* Wl3 = (const float*)d_in[18];
  const float* bl3 = (const float*)d_in[19];
  const float* Wr3 = (const float*)d_in[20];
  const float* g3  = (const float*)d_in[21];
  const float* be3 = (const float*)d_in[22];
  const float* m3  = (const float*)d_in[23];
  const float* v3  = (const float*)d_in[24];
  const float* W4  = (const float*)d_in[25];
  const float* b4  = (const float*)d_in[26];
  const float* W5  = (const float*)d_in[27];
  const float* b5  = (const float*)d_in[28];

  char* ws = (char*)d_ws;
  size_t off = 0;
  auto alloc = [&](size_t bytes) -> void* {
    void* p = (void*)(ws + off);
    off += (bytes + 255) & ~(size_t)255;
    return p;
  };
  int* rowptr3 = (int*)alloc(3 * (NN + 1) * sizeof(int));
  int* cnt3    = (int*)alloc(3 * NN * sizeof(int));
  int* cursor3 = (int*)alloc(3 * NN * sizeof(int));
  int* a0      = (int*)alloc(NE * sizeof(int));
  int* a1      = (int*)alloc(NE * sizeof(int));
  int* a2      = (int*)alloc(NE * sizeof(int));
  int* adj_eid = (int*)alloc(NE * sizeof(int));
  unsigned short* agg1 = (unsigned short*)alloc((size_t)NN * 96 * 2);
  unsigned short* aggH = (unsigned short*)alloc((size_t)NN * 128 * 2);
  unsigned short* h1   = (unsigned short*)alloc((size_t)NN * 128 * 2);
  unsigned short* h2   = (unsigned short*)alloc((size_t)NN * 128 * 2);
  unsigned short* h3   = (unsigned short*)alloc((size_t)NN * 128 * 2);
  unsigned short* xb   = (unsigned short*)alloc((size_t)NN * 64 * 2);
  unsigned short* W1b  = (unsigned short*)alloc(12288 * 2);
  unsigned short* Wl2b = (unsigned short*)alloc(16384 * 2);
  unsigned short* Wr2b = (unsigned short*)alloc(16384 * 2);
  unsigned short* Wl3b = (unsigned short*)alloc(16384 * 2);
  unsigned short* Wr3b = (unsigned short*)alloc(16384 * 2);
  unsigned short* W4b  = (unsigned short*)alloc(12288 * 2);

  const int* rp0 = rowptr3;
  const int* rp1 = rowptr3 + (NN + 1);
  const int* rp2 = rowptr3 + 2 * (NN + 1);

  const int gE    = (NE + 255) / 256;          // 3125
  const int gZ    = (3 * NN + 255) / 256;
  const int gAgg  = (NN * 64) / 256;           // 12500
  const int gTile = (3125 * 8 * 64) / 256;     // 6250
  const int gRead = (3125 * 64 + 255) / 256;   // 782
  const int gCvt  = (CVT_END + 255) / 256;

  k_cvt_all<<<gCvt, 256, 0, stream>>>(x, W1, Wl2, Wr2, Wl3, Wr3, W4,
                                      xb, W1b, Wl2b, Wr2b, Wl3b, Wr3b, W4b);

  // ---- CSR build for all 3 layers (fused) ----
  k_zero<<<gZ, 256, 0, stream>>>(cnt3, 3 * NN);
  k_count3<<<dim3(gE, 3), 256, 0, stream>>>(ei0, ei1, ei2, cnt3);
  k_scan3<<<3, 1024, 0, stream>>>(cnt3, rowptr3, cursor3);
  k_fill3<<<dim3(gE, 3), 256, 0, stream>>>(ei0, ei1, ei2, cursor3, a0, a1, a2, adj_eid);

  // ---- layer 1 (conv1) ----
  k_agg1<<<gAgg, 256, 0, stream>>>(rp0, a0, adj_eid, xb, ea, agg1);
  k_lin1<<<gTile, 256, 0, stream>>>(agg1, W1b, b1, g1, be1, m1, v1, rp0, h1);

  // ---- layer 2 (SAGE) ----
  k_aggH<<<gAgg, 256, 0, stream>>>(rp1, a1, h1, aggH);
  k_sage<<<gTile, 256, 0, stream>>>(aggH, h1, Wl2b, bl2, Wr2b, g2, be2, m2, v2, h2);

  // ---- layer 3 (SAGE) ----
  k_aggH<<<gAgg, 256, 0, stream>>>(rp2, a2, h2, aggH);
  k_sage<<<gTile, 256, 0, stream>>>(aggH, h2, Wl3b, bl3, Wr3b, g3, be3, m3, v3, h3);

  // ---- readout ----
  k_readout<<<gRead, 256, 0, stream>>>(h3, xb, W4b, b4, W5, b5, (float*)d_out);

  (void)in_sizes; (void)n_in; (void)out_size; (void)ws_size;
}

// Round 4
// 600.032 us; speedup vs baseline: 2.1054x; 1.3957x over previous
//
#include <hip/hip_runtime.h>
#include <hip/hip_bf16.h>
#include <stdint.h>

#define NN 50000
#define NE 800000
#define EPS 1e-5f

// CSR bucket build params
#define KB 98        // buckets = ceil(NN / NPB)
#define SH 9         // bucket = dst >> SH
#define NPB 512      // nodes per bucket
#define RCAP 9216    // record slots per bucket (mean 8192, +11 sigma)
#define ACAP 9216    // adj slots per bucket
#define PT 2048      // edges per partition block

typedef __attribute__((ext_vector_type(8))) short bf16x8;
typedef __attribute__((ext_vector_type(4))) float floatx4;

static __device__ __forceinline__ float bf2f(unsigned short u){
  union { unsigned int i; float f; } c; c.i = ((unsigned int)u) << 16; return c.f;
}
static __device__ __forceinline__ unsigned short f2bf(float f){
  union { float f; unsigned int i; } c; c.f = f;
  unsigned int x = c.i;
  return (unsigned short)((x + 0x7fffu + ((x >> 16) & 1u)) >> 16);
}

// fused f32 -> bf16 converter for x + the 6 GEMM weight matrices; also zeros bucket cursors
#define CVT_X   3200000
#define CVT_W1  3212288
#define CVT_WL2 3228672
#define CVT_WR2 3245056
#define CVT_WL3 3261440
#define CVT_WR3 3277824
#define CVT_END 3290112
__global__ void k_cvt_all(const float* __restrict__ x,  const float* __restrict__ W1,
                          const float* __restrict__ Wl2, const float* __restrict__ Wr2,
                          const float* __restrict__ Wl3, const float* __restrict__ Wr3,
                          const float* __restrict__ W4,
                          unsigned short* __restrict__ xb,  unsigned short* __restrict__ W1b,
                          unsigned short* __restrict__ Wl2b, unsigned short* __restrict__ Wr2b,
                          unsigned short* __restrict__ Wl3b, unsigned short* __restrict__ Wr3b,
                          unsigned short* __restrict__ W4b, int* __restrict__ gcur){
  int i = blockIdx.x * 256 + threadIdx.x;
  if(i >= CVT_END) return;
  if(i < 3 * KB) gcur[i] = 0;
  if(i < CVT_X)        xb[i] = f2bf(x[i]);
  else if(i < CVT_W1)  W1b[i - CVT_X]    = f2bf(W1[i - CVT_X]);
  else if(i < CVT_WL2) Wl2b[i - CVT_W1]  = f2bf(Wl2[i - CVT_W1]);
  else if(i < CVT_WR2) Wr2b[i - CVT_WL2] = f2bf(Wr2[i - CVT_WL2]);
  else if(i < CVT_WL3) Wl3b[i - CVT_WR2] = f2bf(Wl3[i - CVT_WR2]);
  else if(i < CVT_WR3) Wr3b[i - CVT_WL3] = f2bf(Wr3[i - CVT_WL3]);
  else                 W4b[i - CVT_WR3]  = f2bf(W4[i - CVT_WR3]);
}

// ---- LDS-staged partition: edges -> bucket-grouped records ----
// L0 variant carries eid: rec = int4 {dst, src, eid, 0}
__global__ void k_part0(const int* __restrict__ ei, int* __restrict__ gcur, int4* __restrict__ rec){
  __shared__ int4 stage[PT];
  __shared__ int hist[KB], ex[KB], cur[KB], gbase[KB];
  __shared__ int tot;
  int tid = threadIdx.x;
  int tile = blockIdx.x * PT;
  for(int i = tid; i < KB; i += 256) hist[i] = 0;
  __syncthreads();
  int dst[8], src[8];
  #pragma unroll
  for(int j = 0; j < 8; j++){
    int e = tile + j * 256 + tid;
    if(e < NE){ src[j] = ei[e]; dst[j] = ei[NE + e]; atomicAdd(&hist[dst[j] >> SH], 1); }
    else dst[j] = -1;
  }
  __syncthreads();
  if(tid == 0){ int run = 0; for(int b = 0; b < KB; b++){ ex[b] = run; cur[b] = run; run += hist[b]; } tot = run; }
  if(tid < KB) gbase[tid] = atomicAdd(&gcur[tid], hist[tid]);
  __syncthreads();
  #pragma unroll
  for(int j = 0; j < 8; j++){
    if(dst[j] >= 0){
      int b = dst[j] >> SH;
      int s = atomicAdd(&cur[b], 1);
      stage[s] = make_int4(dst[j], src[j], tile + j * 256 + tid, 0);
    }
  }
  __syncthreads();
  for(int s = tid; s < tot; s += 256){
    int4 r = stage[s];
    int b = r.x >> SH;
    rec[b * RCAP + gbase[b] + (s - ex[b])] = r;
  }
}

// L1/L2 variant: rec = int2 {dst, src}
__global__ void k_part(const int* __restrict__ ei, int* __restrict__ gcur, int2* __restrict__ rec){
  __shared__ int2 stage[PT];
  __shared__ int hist[KB], ex[KB], cur[KB], gbase[KB];
  __shared__ int tot;
  int tid = threadIdx.x;
  int tile = blockIdx.x * PT;
  for(int i = tid; i < KB; i += 256) hist[i] = 0;
  __syncthreads();
  int dst[8], src[8];
  #pragma unroll
  for(int j = 0; j < 8; j++){
    int e = tile + j * 256 + tid;
    if(e < NE){ src[j] = ei[e]; dst[j] = ei[NE + e]; atomicAdd(&hist[dst[j] >> SH], 1); }
    else dst[j] = -1;
  }
  __syncthreads();
  if(tid == 0){ int run = 0; for(int b = 0; b < KB; b++){ ex[b] = run; cur[b] = run; run += hist[b]; } tot = run; }
  if(tid < KB) gbase[tid] = atomicAdd(&gcur[tid], hist[tid]);
  __syncthreads();
  #pragma unroll
  for(int j = 0; j < 8; j++){
    if(dst[j] >= 0){
      int b = dst[j] >> SH;
      int s = atomicAdd(&cur[b], 1);
      stage[s] = make_int2(dst[j], src[j]);
    }
  }
  __syncthreads();
  for(int s = tid; s < tot; s += 256){
    int2 r = stage[s];
    int b = r.x >> SH;
    rec[b * RCAP + gbase[b] + (s - ex[b])] = r;
  }
}

// ---- per-bucket CSR build: one block per bucket, all scatter stays XCD-local ----
__global__ void k_build0(const int4* __restrict__ rec, const int* __restrict__ gcnt,
                         int2* __restrict__ adj, int* __restrict__ rowbeg, int* __restrict__ deg){
  __shared__ int cnt[NPB], ex2[NPB], cur2[NPB];
  __shared__ int part[256];
  int b = blockIdx.x, tid = threadIdx.x;
  int n0 = b << SH;
  int nr = gcnt[b];
  const int4* r = rec + b * RCAP;
  for(int i = tid; i < NPB; i += 256) cnt[i] = 0;
  __syncthreads();
  for(int k = tid; k < nr; k += 256) atomicAdd(&cnt[r[k].x - n0], 1);
  __syncthreads();
  int c0 = cnt[2 * tid], c1 = cnt[2 * tid + 1];
  part[tid] = c0 + c1;
  __syncthreads();
  for(int d = 1; d < 256; d <<= 1){
    int v = (tid >= d) ? part[tid - d] : 0;
    __syncthreads();
    part[tid] += v;
    __syncthreads();
  }
  int base = part[tid] - c0 - c1;
  ex2[2 * tid] = base;          cur2[2 * tid] = base;
  ex2[2 * tid + 1] = base + c0; cur2[2 * tid + 1] = base + c0;
  __syncthreads();
  for(int i = tid; i < NPB; i += 256){
    int n = n0 + i;
    if(n < NN){ rowbeg[n] = b * ACAP + ex2[i]; deg[n] = cnt[i]; }
  }
  for(int k = tid; k < nr; k += 256){
    int4 q = r[k];
    int p = atomicAdd(&cur2[q.x - n0], 1);
    adj[b * ACAP + p] = make_int2(q.y, q.z);
  }
}

__global__ void k_build(const int2* __restrict__ rec, const int* __restrict__ gcnt,
                        int* __restrict__ adj, int* __restrict__ rowbeg, int* __restrict__ deg){
  __shared__ int cnt[NPB], ex2[NPB], cur2[NPB];
  __shared__ int part[256];
  int b = blockIdx.x, tid = threadIdx.x;
  int n0 = b << SH;
  int nr = gcnt[b];
  const int2* r = rec + b * RCAP;
  for(int i = tid; i < NPB; i += 256) cnt[i] = 0;
  __syncthreads();
  for(int k = tid; k < nr; k += 256) atomicAdd(&cnt[r[k].x - n0], 1);
  __syncthreads();
  int c0 = cnt[2 * tid], c1 = cnt[2 * tid + 1];
  part[tid] = c0 + c1;
  __syncthreads();
  for(int d = 1; d < 256; d <<= 1){
    int v = (tid >= d) ? part[tid - d] : 0;
    __syncthreads();
    part[tid] += v;
    __syncthreads();
  }
  int base = part[tid] - c0 - c1;
  ex2[2 * tid] = base;          cur2[2 * tid] = base;
  ex2[2 * tid + 1] = base + c0; cur2[2 * tid + 1] = base + c0;
  __syncthreads();
  for(int i = tid; i < NPB; i += 256){
    int n = n0 + i;
    if(n < NN){ rowbeg[n] = b * ACAP + ex2[i]; deg[n] = cnt[i]; }
  }
  for(int k = tid; k < nr; k += 256){
    int2 q = r[k];
    int p = atomicAdd(&cur2[q.x - n0], 1);
    adj[b * ACAP + p] = q.y;
  }
}

// conv1 aggregation: mean over incoming edges of [x[src](64, bf16) | edge_attr[e](32, f32)]
// adj entries are int2 {src, eid}; 8-way MLP unroll
__global__ void k_agg1(const int* __restrict__ rowbeg, const int* __restrict__ deg,
                       const int2* __restrict__ adj,
                       const unsigned short* __restrict__ xb, const float* __restrict__ ea,
                       unsigned short* __restrict__ agg){
  int w = (blockIdx.x * blockDim.x + threadIdx.x) >> 6;
  int lane = threadIdx.x & 63;
  if(w >= NN) return;
  int r0 = rowbeg[w], dg = deg[w], r1 = r0 + dg;
  float ax = 0.f, ay = 0.f;
  if(lane < 32){
    int c = 2 * lane;
    int k = r0;
    for(; k + 8 <= r1; k += 8){
      int s[8]; unsigned int v[8];
      #pragma unroll
      for(int j = 0; j < 8; j++) s[j] = adj[k + j].x;
      #pragma unroll
      for(int j = 0; j < 8; j++) v[j] = *(const unsigned int*)(xb + s[j] * 64 + c);
      #pragma unroll
      for(int j = 0; j < 8; j++){ ax += bf2f((unsigned short)(v[j] & 0xffffu)); ay += bf2f((unsigned short)(v[j] >> 16)); }
    }
    for(; k < r1; k++){
      unsigned int v = *(const unsigned int*)(xb + adj[k].x * 64 + c);
      ax += bf2f((unsigned short)(v & 0xffffu)); ay += bf2f((unsigned short)(v >> 16));
    }
  } else if(lane < 48){
    int c = 2 * (lane - 32);
    int k = r0;
    for(; k + 8 <= r1; k += 8){
      int e[8]; float2 v[8];
      #pragma unroll
      for(int j = 0; j < 8; j++) e[j] = adj[k + j].y;
      #pragma unroll
      for(int j = 0; j < 8; j++) v[j] = *(const float2*)(ea + e[j] * 32 + c);
      #pragma unroll
      for(int j = 0; j < 8; j++){ ax += v[j].x; ay += v[j].y; }
    }
    for(; k < r1; k++){
      float2 v = *(const float2*)(ea + adj[k].y * 32 + c);
      ax += v.x; ay += v.y;
    }
  }
  if(lane < 48){
    float inv = 1.0f / (float)(dg > 0 ? dg : 1);
    int col = (lane < 32) ? 2 * lane : 64 + 2 * (lane - 32);
    unsigned int packed = (unsigned int)f2bf(ax * inv) | ((unsigned int)f2bf(ay * inv) << 16);
    *(unsigned int*)(agg + w * 96 + col) = packed;
  }
}

// mean-aggregate 128-dim bf16 node features; one wave per node, lane l owns dims 2l,2l+1
__global__ void k_aggH(const int* __restrict__ rowbeg, const int* __restrict__ deg,
                       const int* __restrict__ adj,
                       const unsigned short* __restrict__ h, unsigned short* __restrict__ agg){
  int w = (blockIdx.x * blockDim.x + threadIdx.x) >> 6;
  int lane = threadIdx.x & 63;
  if(w >= NN) return;
  int r0 = rowbeg[w], dg = deg[w], r1 = r0 + dg;
  float ax = 0.f, ay = 0.f;
  int c = 2 * lane;
  int k = r0;
  for(; k + 8 <= r1; k += 8){
    int s[8]; unsigned int v[8];
    #pragma unroll
    for(int j = 0; j < 8; j++) s[j] = adj[k + j];
    #pragma unroll
    for(int j = 0; j < 8; j++) v[j] = *(const unsigned int*)(h + s[j] * 128 + c);
    #pragma unroll
    for(int j = 0; j < 8; j++){ ax += bf2f((unsigned short)(v[j] & 0xffffu)); ay += bf2f((unsigned short)(v[j] >> 16)); }
  }
  for(; k < r1; k++){
    unsigned int v = *(const unsigned int*)(h + adj[k] * 128 + c);
    ax += bf2f((unsigned short)(v & 0xffffu)); ay += bf2f((unsigned short)(v >> 16));
  }
  float inv = 1.0f / (float)(dg > 0 ? dg : 1);
  unsigned int packed = (unsigned int)f2bf(ax * inv) | ((unsigned int)f2bf(ay * inv) << 16);
  *(unsigned int*)(agg + w * 128 + c) = packed;
}

// conv1 dense part: h1 = relu(bn(relu(mask_deg(agg @ W1^T + b1))))
__global__ void k_lin1(const unsigned short* __restrict__ agg, const unsigned short* __restrict__ W1,
                       const float* __restrict__ b1,
                       const float* __restrict__ g1, const float* __restrict__ be1,
                       const float* __restrict__ m1, const float* __restrict__ v1,
                       const int* __restrict__ deg, unsigned short* __restrict__ h1){
  int wave = (blockIdx.x * blockDim.x + threadIdx.x) >> 6;
  int lane = threadIdx.x & 63;
  int mt = wave >> 3, nt = wave & 7;
  if(mt >= 3125) return;
  int node0 = mt * 16;
  int col = lane & 15, quad = lane >> 4;
  int o = nt * 16 + col;
  int arow = node0 + col;
  floatx4 acc = {0.f, 0.f, 0.f, 0.f};
  #pragma unroll
  for(int kc = 0; kc < 3; kc++){
    bf16x8 a = *(const bf16x8*)(agg + arow * 96 + kc * 32 + quad * 8);
    bf16x8 b = *(const bf16x8*)(W1 + o * 96 + kc * 32 + quad * 8);
    acc = __builtin_amdgcn_mfma_f32_16x16x32_bf16(a, b, acc, 0, 0, 0);
  }
  float bb = b1[o];
  float sc = g1[o] * rsqrtf(v1[o] + EPS);
  float mv = m1[o], bev = be1[o];
  #pragma unroll
  for(int r = 0; r < 4; r++){
    int node = node0 + quad * 4 + r;
    float pre = (deg[node] > 0) ? (acc[r] + bb) : 0.0f;   // ref: empty segment -> mean 0, bias never added
    float t = fmaxf(pre, 0.f);
    float bn = sc * (t - mv) + bev;
    h1[node * 128 + o] = f2bf(fmaxf(bn, 0.f));
  }
}

// SAGE: hout = relu(bn(agg @ Wl^T + bl + hin @ Wr^T))
__global__ void k_sage(const unsigned short* __restrict__ agg, const unsigned short* __restrict__ hin,
                       const unsigned short* __restrict__ Wl, const float* __restrict__ bl,
                       const unsigned short* __restrict__ Wr,
                       const float* __restrict__ g, const float* __restrict__ be,
                       const float* __restrict__ m, const float* __restrict__ v,
                       unsigned short* __restrict__ hout){
  int wave = (blockIdx.x * blockDim.x + threadIdx.x) >> 6;
  int lane = threadIdx.x & 63;
  int mt = wave >> 3, nt = wave & 7;
  if(mt >= 3125) return;
  int node0 = mt * 16;
  int col = lane & 15, quad = lane >> 4;
  int o = nt * 16 + col;
  int arow = node0 + col;
  floatx4 acc = {0.f, 0.f, 0.f, 0.f};
  #pragma unroll
  for(int kc = 0; kc < 4; kc++){
    bf16x8 a = *(const bf16x8*)(agg + arow * 128 + kc * 32 + quad * 8);
    bf16x8 b = *(const bf16x8*)(Wl + o * 128 + kc * 32 + quad * 8);
    acc = __builtin_amdgcn_mfma_f32_16x16x32_bf16(a, b, acc, 0, 0, 0);
  }
  #pragma unroll
  for(int kc = 0; kc < 4; kc++){
    bf16x8 a = *(const bf16x8*)(hin + arow * 128 + kc * 32 + quad * 8);
    bf16x8 b = *(const bf16x8*)(Wr + o * 128 + kc * 32 + quad * 8);
    acc = __builtin_amdgcn_mfma_f32_16x16x32_bf16(a, b, acc, 0, 0, 0);
  }
  float blv = bl[o];
  float sc = g[o] * rsqrtf(v[o] + EPS);
  float mv = m[o], bev = be[o];
  #pragma unroll
  for(int r = 0; r < 4; r++){
    int node = node0 + quad * 4 + r;
    float pre = acc[r] + blv;
    float bn = sc * (pre - mv) + bev;
    hout[node * 128 + o] = f2bf(fmaxf(bn, 0.f));
  }
}

// readout: z = relu([h3 | x] @ W4^T + b4) (64), out = z @ W5^T + b5  (f32 out)
__global__ void k_readout(const unsigned short* __restrict__ h3, const unsigned short* __restrict__ xb,
                          const unsigned short* __restrict__ W4, const float* __restrict__ b4,
                          const float* __restrict__ W5, const float* __restrict__ b5,
                          float* __restrict__ out){
  int wave = (blockIdx.x * blockDim.x + threadIdx.x) >> 6;
  int lane = threadIdx.x & 63;
  if(wave >= 3125) return;
  int node0 = wave * 16;
  int col = lane & 15, quad = lane >> 4;
  int arow = node0 + col;
  float partial[4] = {0.f, 0.f, 0.f, 0.f};
  #pragma unroll
  for(int nt = 0; nt < 4; nt++){
    int o = nt * 16 + col;
    floatx4 acc = {0.f, 0.f, 0.f, 0.f};
    #pragma unroll
    for(int kc = 0; kc < 4; kc++){
      bf16x8 a = *(const bf16x8*)(h3 + arow * 128 + kc * 32 + quad * 8);
      bf16x8 b = *(const bf16x8*)(W4 + o * 192 + kc * 32 + quad * 8);
      acc = __builtin_amdgcn_mfma_f32_16x16x32_bf16(a, b, acc, 0, 0, 0);
    }
    #pragma unroll
    for(int kc = 0; kc < 2; kc++){
      bf16x8 a = *(const bf16x8*)(xb + arow * 64 + kc * 32 + quad * 8);
      bf16x8 b = *(const bf16x8*)(W4 + o * 192 + 128 + kc * 32 + quad * 8);
      acc = __builtin_amdgcn_mfma_f32_16x16x32_bf16(a, b, acc, 0, 0, 0);
    }
    float bb = b4[o];
    float w5 = W5[o];
    #pragma unroll
    for(int r = 0; r < 4; r++)
      partial[r] += fmaxf(acc[r] + bb, 0.f) * w5;
  }
  #pragma unroll
  for(int d = 1; d < 16; d <<= 1){
    #pragma unroll
    for(int r = 0; r < 4; r++)
      partial[r] += __shfl_xor(partial[r], d, 64);
  }
  if(col == 0){
    float b5f = b5[0];
    #pragma unroll
    for(int r = 0; r < 4; r++)
      out[node0 + quad * 4 + r] = partial[r] + b5f;
  }
}

extern "C" void kernel_launch(void* const* d_in, const int* in_sizes, int n_in,
                              void* d_out, int out_size, void* d_ws, size_t ws_size,
                              hipStream_t stream) {
  const float* x   = (const float*)d_in[0];
  const int* ei0   = (const int*)d_in[1];
  const int* ei1   = (const int*)d_in[2];
  const int* ei2   = (const int*)d_in[3];
  const float* ea  = (const float*)d_in[4];
  const float* W1  = (const float*)d_in[5];
  const float* b1  = (const float*)d_in[6];
  const float* g1  = (const float*)d_in[7];
  const float* be1 = (const float*)d_in[8];
  const float* m1  = (const float*)d_in[9];
  const float* v1  = (const float*)d_in[10];
  const float* Wl2 = (const float*)d_in[11];
  const float* bl2 = (const float*)d_in[12];
  const float* Wr2 = (const float*)d_in[13];
  const float* g2  = (const float*)d_in[14];
  const float* be2 = (const float*)d_in[15];
  const float* m2  = (const float*)d_in[16];
  const float* v2  = (const float*)d_in[17];
  const float* Wl3 = (const float*)d_in[18];
  const float* bl3 = (const float*)d_in[19];
  const float* Wr3 = (const float*)d_in[20];
  const float* g3  = (const float*)d_in[21];
  const float* be3 = (const float*)d_in[22];
  const float* m3  = (const float*)d_in[23];
  const float* v3  = (const float*)d_in[24];
  const float* W4  = (const float*)d_in[25];
  const float* b4  = (const float*)d_in[26];
  const float* W5  = (const float*)d_in[27];
  const float* b5  = (const float*)d_in[28];

  char* ws = (char*)d_ws;
  size_t off = 0;
  auto alloc = [&](size_t bytes) -> void* {
    void* p = (void*)(ws + off);
    off += (bytes + 255) & ~(size_t)255;
    return p;
  };
  int* gcur    = (int*)alloc(3 * KB * sizeof(int));
  int* rowbeg3 = (int*)alloc(3 * NN * sizeof(int));
  int* deg3    = (int*)alloc(3 * NN * sizeof(int));
  int4* rec4   = (int4*)alloc((size_t)KB * RCAP * 16);   // reused: int2 recs for L1/L2; h3 aliases after P3(L2)
  int2* adj2   = (int2*)alloc((size_t)KB * ACAP * 8);    // reused: int adj for L1/L2
  unsigned short* agg1 = (unsigned short*)alloc((size_t)NN * 96 * 2);
  unsigned short* aggH = (unsigned short*)alloc((size_t)NN * 128 * 2);
  unsigned short* h1   = (unsigned short*)alloc((size_t)NN * 128 * 2);
  unsigned short* h2   = (unsigned short*)alloc((size_t)NN * 128 * 2);
  unsigned short* xb   = (unsigned short*)alloc((size_t)NN * 64 * 2);
  unsigned short* W1b  = (unsigned short*)alloc(12288 * 2);
  unsigned short* Wl2b = (unsigned short*)alloc(16384 * 2);
  unsigned short* Wr2b = (unsigned short*)alloc(16384 * 2);
  unsigned short* Wl3b = (unsigned short*)alloc(16384 * 2);
  unsigned short* Wr3b = (unsigned short*)alloc(16384 * 2);
  unsigned short* W4b  = (unsigned short*)alloc(12288 * 2);

  int2* rec2 = (int2*)rec4;
  int*  adjI = (int*)adj2;
  unsigned short* h3 = (unsigned short*)rec4;  // alias: rec dead after k_build(L2), h3 written after

  int* rb0 = rowbeg3;            int* dg0 = deg3;
  int* rb1 = rowbeg3 + NN;       int* dg1 = deg3 + NN;
  int* rb2 = rowbeg3 + 2 * NN;   int* dg2 = deg3 + 2 * NN;

  const int gP    = (NE + PT - 1) / PT;        // 391
  const int gAgg  = (NN * 64) / 256;           // 12500
  const int gTile = (3125 * 8 * 64) / 256;     // 6250
  const int gRead = (3125 * 64 + 255) / 256;   // 782
  const int gCvt  = (CVT_END + 255) / 256;

  k_cvt_all<<<gCvt, 256, 0, stream>>>(x, W1, Wl2, Wr2, Wl3, Wr3, W4,
                                      xb, W1b, Wl2b, Wr2b, Wl3b, Wr3b, W4b, gcur);

  // ---- layer 1 (conv1) ----
  k_part0<<<gP, 256, 0, stream>>>(ei0, gcur, rec4);
  k_build0<<<KB, 256, 0, stream>>>(rec4, gcur, adj2, rb0, dg0);
  k_agg1<<<gAgg, 256, 0, stream>>>(rb0, dg0, adj2, xb, ea, agg1);
  k_lin1<<<gTile, 256, 0, stream>>>(agg1, W1b, b1, g1, be1, m1, v1, dg0, h1);

  // ---- layer 2 (SAGE) ----
  k_part<<<gP, 256, 0, stream>>>(ei1, gcur + KB, rec2);
  k_build<<<KB, 256, 0, stream>>>(rec2, gcur + KB, adjI, rb1, dg1);
  k_aggH<<<gAgg, 256, 0, stream>>>(rb1, dg1, adjI, h1, aggH);
  k_sage<<<gTile, 256, 0, stream>>>(aggH, h1, Wl2b, bl2, Wr2b, g2, be2, m2, v2, h2);

  // ---- layer 3 (SAGE) ----
  k_part<<<gP, 256, 0, stream>>>(ei2, gcur + 2 * KB, rec2);
  k_build<<<KB, 256, 0, stream>>>(rec2, gcur + 2 * KB, adjI, rb2, dg2);
  k_aggH<<<gAgg, 256, 0, stream>>>(rb2, dg2, adjI, h2, aggH);
  k_sage<<<gTile, 256, 0, stream>>>(aggH, h2, Wl3b, bl3, Wr3b, g3, be3, m3, v3, h3);

  // ---- readout ----
  k_readout<<<gRead, 256, 0, stream>>>(h3, xb, W4b, b4, W5, b5, (float*)d_out);

  (void)in_sizes; (void)n_in; (void)out_size; (void)ws_size;
}